// Round 8
// baseline (69.546 us; speedup 1.0000x reference)
//
#include <hip/hip_runtime.h>
#include <hip/hip_bf16.h>
#include <cstdint>

#define B_    4
#define NH    8
#define N_TOK 2304
#define D_    32
#define C_    256
#define M_ROWS (B_ * N_TOK)   // 9216
#define KVB   128
#define NT2   (N_TOK / KVB)   // 18
#define M_FIX 10.0f           // fixed softmax max (exp2 domain); scores ~N(0,1.44), |s|<~9

typedef float  f32x4  __attribute__((ext_vector_type(4)));
typedef short  bf16x8 __attribute__((ext_vector_type(8)));

#define GLOADLDS(g, l) __builtin_amdgcn_global_load_lds( \
    (const __attribute__((address_space(1))) unsigned*)(g), \
    (__attribute__((address_space(3))) unsigned*)(l), 16, 0, 0)

static __device__ __forceinline__ unsigned short f2bf(float f) {
    union { float f; unsigned u; } v; v.f = f;
    unsigned u = v.u;
    u += 0x7FFF + ((u >> 16) & 1);   // round-to-nearest-even
    return (unsigned short)(u >> 16);
}

// hardware packed f32->bf16 (RTNE), lo = a, hi = b
static __device__ __forceinline__ unsigned cvt_pk_bf16(float a, float b) {
    unsigned r;
    asm("v_cvt_pk_bf16_f32 %0, %1, %2" : "=v"(r) : "v"(a), "v"(b));
    return r;
}

// ---------------- prep: X fp32 -> bf16 ----------------
__global__ void k_prep_x(const float* __restrict__ x, unsigned short* __restrict__ xb) {
    int i = blockIdx.x * blockDim.x + threadIdx.x;    // one float4 per thread
    float4 v = reinterpret_cast<const float4*>(x)[i];
    ushort4 o;
    o.x = f2bf(v.x); o.y = f2bf(v.y); o.z = f2bf(v.z); o.w = f2bf(v.w);
    reinterpret_cast<ushort4*>(xb)[i] = o;
}

// ---------------- prep: W[c][d] fp32 -> Wt[d][c] bf16 (3 matrices) ----------------
// Output wt is [768][256]: row = concat output col (Q 0-255 | K 256-511 | V 512-767).
__global__ void k_prep_w(const float* __restrict__ w0, const float* __restrict__ w1,
                         const float* __restrict__ w2, unsigned short* __restrict__ wt) {
    __shared__ float tile[64][65];
    int mat = blockIdx.y;
    const float* w = (mat == 0) ? w0 : (mat == 1) ? w1 : w2;
    int t   = blockIdx.x;           // 0..15
    int tc  = (t & 3) * 64;         // c-tile base
    int td  = (t >> 2) * 64;        // d-tile base
    int tid = threadIdx.x;
    int r0  = tid >> 6;             // 0..3
    int x0  = tid & 63;
#pragma unroll
    for (int it = 0; it < 16; ++it) {
        int c = it * 4 + r0;
        tile[c][x0] = w[(tc + c) * C_ + td + x0];
    }
    __syncthreads();
    unsigned short* wto = wt + mat * (C_ * C_);
#pragma unroll
    for (int it = 0; it < 16; ++it) {
        int d = it * 4 + r0;
        wto[(td + d) * C_ + tc + x0] = f2bf(tile[x0][d]);
    }
}

// ---------------- QKV projection: LDS-staged dbuf MFMA GEMM 9216x768x256 ----------------
// grid (144, 6). Block: 64 rows x 128 cols; 4 waves 2x2, wave = 32x64 (2x4 frags).
__global__ __launch_bounds__(256) void k_proj(
    const unsigned short* __restrict__ xb,
    const unsigned short* __restrict__ wtb,
    const float* __restrict__ bq, const float* __restrict__ bk, const float* __restrict__ bv,
    unsigned short* __restrict__ qo, unsigned short* __restrict__ ko, unsigned short* __restrict__ vto)
{
    __shared__ __align__(16) unsigned short A_lds[2][64][32];    // 8 KB
    __shared__ __align__(16) unsigned short B_lds[2][128][32];   // 16 KB

    int rows0 = blockIdx.x * 64;
    int cols0 = blockIdx.y * 128;
    int mat   = cols0 >> 8;                   // constant per block (128 | 256)
    const float* bias = (mat == 0) ? bq : (mat == 1) ? bk : bv;
    float scale = (mat == 0) ? (0.17677669529663687f * 1.4426950408889634f) : 1.0f;

    int tid = threadIdx.x, wave = tid >> 6, lane = tid & 63;
    int lr = lane & 15, lg = lane >> 4;
    int wr = wave >> 1, wc = wave & 1;

    int srow = lane >> 2, sslot = lane & 3;
    int ra   = wave * 16 + srow;
    int keyA = ((ra >> 1) & 1) | (((ra >> 3) & 1) << 1);
    const unsigned short* asrc = xb + (rows0 + ra) * C_ + ((sslot ^ keyA) * 8);
    int rb   = wave * 32 + srow;
    int keyB0 = ((rb >> 1) & 1) | (((rb >> 3) & 1) << 1);
    int keyB1 = (((rb + 16) >> 1) & 1) | ((((rb + 16) >> 3) & 1) << 1);
    const unsigned short* bsrc0 = wtb + (cols0 + rb) * C_ + ((sslot ^ keyB0) * 8);
    const unsigned short* bsrc1 = wtb + (cols0 + rb + 16) * C_ + ((sslot ^ keyB1) * 8);

    char* aldsb = (char*)&A_lds[0][0][0];
    char* bldsb = (char*)&B_lds[0][0][0];
    int adst = wave * 1024;
    int bdst0 = wave * 2048, bdst1 = bdst0 + 1024;

    int xorb = (((lr >> 1) & 1) << 4) | (((lr >> 3) & 1) << 5);
    int fcol = (lg * 16) ^ xorb;
    int arow0 = wr * 32 + lr;
    int brow0 = wc * 64 + lr;

    GLOADLDS(asrc, aldsb + adst);
    GLOADLDS(bsrc0, bldsb + bdst0);
    GLOADLDS(bsrc1, bldsb + bdst1);
    __syncthreads();

    f32x4 acc[2][4];
#pragma unroll
    for (int i = 0; i < 2; ++i)
#pragma unroll
        for (int j = 0; j < 4; ++j) acc[i][j] = (f32x4){0.f, 0.f, 0.f, 0.f};

    int buf = 0;
    for (int ks = 0; ks < 8; ++ks) {
        if (ks < 7) {
            int ko_ = (ks + 1) * 32;
            char* ad = aldsb + (buf ^ 1) * 4096;
            char* bd = bldsb + (buf ^ 1) * 8192;
            GLOADLDS(asrc + ko_, ad + adst);
            GLOADLDS(bsrc0 + ko_, bd + bdst0);
            GLOADLDS(bsrc1 + ko_, bd + bdst1);
        }
        const char* ac = aldsb + buf * 4096;
        const char* bc = bldsb + buf * 8192;

        bf16x8 a[2], b[4];
#pragma unroll
        for (int fr = 0; fr < 2; ++fr)
            a[fr] = *reinterpret_cast<const bf16x8*>(ac + (arow0 + fr * 16) * 64 + fcol);
#pragma unroll
        for (int fn = 0; fn < 4; ++fn)
            b[fn] = *reinterpret_cast<const bf16x8*>(bc + (brow0 + fn * 16) * 64 + fcol);

        __builtin_amdgcn_s_setprio(1);
#pragma unroll
        for (int fr = 0; fr < 2; ++fr)
#pragma unroll
            for (int fn = 0; fn < 4; ++fn)
                acc[fr][fn] = __builtin_amdgcn_mfma_f32_16x16x32_bf16(a[fr], b[fn], acc[fr][fn], 0, 0, 0);
        __builtin_amdgcn_s_setprio(0);

        __syncthreads();
        buf ^= 1;
    }

    int bidx = rows0 / N_TOK;
    int nb   = rows0 - bidx * N_TOK + wr * 32 + lg * 4;

    if (mat == 2) {
#pragma unroll
        for (int fr = 0; fr < 2; ++fr)
#pragma unroll
            for (int fn = 0; fn < 4; ++fn) {
                int cm = (cols0 & 255) + wc * 64 + fn * 16 + lr;
                float bsv = bias[cm];
                int hh = cm >> 5, d = cm & 31;
                uint2 pr;
                pr.x = cvt_pk_bf16(acc[fr][fn][0] + bsv, acc[fr][fn][1] + bsv);
                pr.y = cvt_pk_bf16(acc[fr][fn][2] + bsv, acc[fr][fn][3] + bsv);
                *reinterpret_cast<uint2*>(vto + ((bidx * NH + hh) * D_ + d) * N_TOK + nb + fr * 16) = pr;
            }
    } else {
        unsigned short* dst = (mat == 0) ? qo : ko;
#pragma unroll
        for (int fr = 0; fr < 2; ++fr)
#pragma unroll
            for (int fn = 0; fn < 4; ++fn) {
                int cm = (cols0 & 255) + wc * 64 + fn * 16 + lr;
                float bsv = bias[cm];
                int hh = cm >> 5, d = cm & 31;
#pragma unroll
                for (int j = 0; j < 4; ++j) {
                    float val = (acc[fr][fn][j] + bsv) * scale;
                    dst[((bidx * NH + hh) * N_TOK + nb + fr * 16 + j) * D_ + d] = f2bf(val);
                }
            }
    }
}

// ---------------- fused flash attention + residual epilogue ----------------
// 8 waves / 512 threads, 128 q-rows per block, grid 576. Waves 0-3 stage K,
// waves 4-7 stage Vt (2 x global_load_lds each). Swapped QK^T with PERMUTED
// K rows (s IS the PV A-fragment). FIXED-MAX softmax (C-init = -M_FIX),
// row-sum l via MFMA with B=ones. exp2/cvt/PV interleaved per kseg.
__global__ __launch_bounds__(512, 8) void k_attn(
    const unsigned short* __restrict__ qb,
    const unsigned short* __restrict__ kb,
    const unsigned short* __restrict__ vtg,   // [bh][32][2304]
    const float* __restrict__ x,
    const float* __restrict__ gamma_p,
    float* __restrict__ out)
{
    __shared__ __align__(16) unsigned short K_lds[2][KVB][32];    // 16 KB
    __shared__ __align__(16) unsigned short Vt_lds[2][32][KVB];   // 16 KB

    // bijective XCD swizzle: 576 workgroups, 8 XCDs, 72 per XCD
    int wid = (blockIdx.x & 7) * 72 + (blockIdx.x >> 3);
    int bh  = wid / 18;              // b*8 + head
    int qb0 = (wid % 18) * 128;

    int tid = threadIdx.x, wave = tid >> 6, lane = tid & 63;
    int lr = lane & 15, lg = lane >> 4;

    const unsigned short* Q  = qb  + bh * N_TOK * D_;
    const unsigned short* K  = kb  + bh * N_TOK * D_;
    const unsigned short* Vt = vtg + bh * D_ * N_TOK;

    // Q as B-operand: lane holds Q[q=lr][8*lg+i]
    int qrow = qb0 + wave * 16 + lr;
    bf16x8 q_frag = *reinterpret_cast<const bf16x8*>(Q + qrow * D_ + lg * 8);

    // ---- staging: waves 0-3 stage K chunks, waves 4-7 stage Vt chunks ----
    bool stK = wave < 4;
    int  sw  = stK ? wave : (wave - 4);
    int c0   = sw * 2;
    // K rows 32sw+(lane>>2), +16 (key bits {1,3} identical for +16)
    int kr0  = 32 * sw + (lane >> 2);
    int kslot = ((kr0 >> 1) & 1) | (((kr0 >> 3) & 1) << 1);
    int koff0 = kr0 * D_ + (((lane & 3) ^ kslot) * 8);
    int koff1 = koff0 + 16 * D_;
    // Vt rows 8sw+(lane>>4), +4
    int vr0   = 8 * sw + (lane >> 4);
    int voff0 = vr0 * N_TOK + (((lane & 15) ^ (vr0 & 7)) * 8);
    int voff1 = (vr0 + 4) * N_TOK + (((lane & 15) ^ ((vr0 + 4) & 7)) * 8);

    char* kldsb = (char*)&K_lds[0][0][0];
    char* vldsb = (char*)&Vt_lds[0][0][0];
    int dst0 = c0 * 1024, dst1 = dst0 + 1024;

    // prologue: stage tile 0 into buffer 0
    if (stK) {
        GLOADLDS(K + koff0, kldsb + dst0);
        GLOADLDS(K + koff1, kldsb + dst1);
    } else {
        GLOADLDS(Vt + voff0, vldsb + dst0);
        GLOADLDS(Vt + voff1, vldsb + dst1);
    }
    __syncthreads();

    f32x4 acc0  = (f32x4){0.f, 0.f, 0.f, 0.f};   // d = lr      , q = 4lg+j
    f32x4 acc1  = (f32x4){0.f, 0.f, 0.f, 0.f};   // d = 16 + lr , q = 4lg+j
    f32x4 acc_l = (f32x4){0.f, 0.f, 0.f, 0.f};   // l(q=4lg+j), replicated over lr

    union { unsigned w[4]; bf16x8 v; } ones;
    ones.w[0] = 0x3F803F80u; ones.w[1] = 0x3F803F80u;
    ones.w[2] = 0x3F803F80u; ones.w[3] = 0x3F803F80u;

    // K read: row R(kt,lr) swizzled; per-lane part precomputed
    int kread_key = (((lr >> 1) & 1) << 4) | (((lr >> 2) & 1) << 5);
    int krow_lane = (8 * (lr >> 2) + (lr & 3)) * 64 + ((lg * 16) ^ kread_key);
    int vkey = (lr & 7) << 4;

    const f32x4 zinit = (f32x4){-M_FIX, -M_FIX, -M_FIX, -M_FIX};

    int buf = 0;
    for (int t = 0; t < NT2; ++t) {
        // async-stage next tile into other buffer (drained by end-of-iter barrier)
        if (t < NT2 - 1) {
            if (stK) {
                const unsigned short* Kn = K + (t + 1) * (KVB * D_);
                char* kd = kldsb + (buf ^ 1) * 8192;
                GLOADLDS(Kn + koff0, kd + dst0);
                GLOADLDS(Kn + koff1, kd + dst1);
            } else {
                const unsigned short* Vn = Vt + (t + 1) * KVB;
                char* vd = vldsb + (buf ^ 1) * 8192;
                GLOADLDS(Vn + voff0, vd + dst0);
                GLOADLDS(Vn + voff1, vd + dst1);
            }
        }
        const char* kc = kldsb + buf * 8192;
        const char* vc = vldsb + buf * 8192;

        // ---- S^T = K*Q - M : s[kt][j] = S[q=lr][32(kt>>1)+4(kt&1)+8lg+j] - M ----
        f32x4 s[8];
        __builtin_amdgcn_s_setprio(1);
#pragma unroll
        for (int kt = 0; kt < 8; ++kt) {
            bf16x8 kf = *reinterpret_cast<const bf16x8*>(
                kc + (kt >> 1) * 2048 + (kt & 1) * 256 + krow_lane);
            s[kt] = __builtin_amdgcn_mfma_f32_16x16x32_bf16(kf, q_frag, zinit, 0, 0, 0);
        }
        __builtin_amdgcn_s_setprio(0);

        // ---- per kseg: exp2 (TRANS) -> cvt_pk -> PV (MFMA); TRANS of kseg g+1
        //      overlaps MFMA drain of kseg g ----
#pragma unroll
        for (int kseg = 0; kseg < 4; ++kseg) {
            float e0 = __builtin_amdgcn_exp2f(s[2 * kseg][0]);
            float e1 = __builtin_amdgcn_exp2f(s[2 * kseg][1]);
            float e2 = __builtin_amdgcn_exp2f(s[2 * kseg][2]);
            float e3 = __builtin_amdgcn_exp2f(s[2 * kseg][3]);
            float e4 = __builtin_amdgcn_exp2f(s[2 * kseg + 1][0]);
            float e5 = __builtin_amdgcn_exp2f(s[2 * kseg + 1][1]);
            float e6 = __builtin_amdgcn_exp2f(s[2 * kseg + 1][2]);
            float e7 = __builtin_amdgcn_exp2f(s[2 * kseg + 1][3]);
            union { unsigned w[4]; bf16x8 v; } pa;
            pa.w[0] = cvt_pk_bf16(e0, e1);
            pa.w[1] = cvt_pk_bf16(e2, e3);
            pa.w[2] = cvt_pk_bf16(e4, e5);
            pa.w[3] = cvt_pk_bf16(e6, e7);
            int off = (kseg * 64 + lg * 16) ^ vkey;
            bf16x8 vf0 = *reinterpret_cast<const bf16x8*>(vc + lr * 256 + off);
            bf16x8 vf1 = *reinterpret_cast<const bf16x8*>(vc + (16 + lr) * 256 + off);
            acc0  = __builtin_amdgcn_mfma_f32_16x16x32_bf16(pa.v, vf0,    acc0,  0, 0, 0);
            acc1  = __builtin_amdgcn_mfma_f32_16x16x32_bf16(pa.v, vf1,    acc1,  0, 0, 0);
            acc_l = __builtin_amdgcn_mfma_f32_16x16x32_bf16(pa.v, ones.v, acc_l, 0, 0, 0);
        }

        __syncthreads();   // drains vmcnt -> staged tile visible; LDS reuse safe
        buf ^= 1;
    }

    // ---- epilogue: out = gamma * (O / l) + x  (l already in q=4lg+j domain) ----
    float g = gamma_p[0];
    int b = bh >> 3, head = bh & 7;
#pragma unroll
    for (int j = 0; j < 4; ++j) {
        float linv = 1.0f / acc_l[j];
        int n = qb0 + wave * 16 + 4 * lg + j;
        long r = (long)(b * N_TOK + n) * C_ + head * 32;
        out[r + lr]      = g * (acc0[j] * linv) + x[r + lr];
        out[r + 16 + lr] = g * (acc1[j] * linv) + x[r + 16 + lr];
    }
}

extern "C" void kernel_launch(void* const* d_in, const int* in_sizes, int n_in,
                              void* d_out, int out_size, void* d_ws, size_t ws_size,
                              hipStream_t stream) {
    const float* x     = (const float*)d_in[0];
    const float* wq    = (const float*)d_in[1];
    const float* bq    = (const float*)d_in[2];
    const float* wk    = (const float*)d_in[3];
    const float* bk    = (const float*)d_in[4];
    const float* wv    = (const float*)d_in[5];
    const float* bv    = (const float*)d_in[6];
    const float* gamma = (const float*)d_in[7];
    float* out = (float*)d_out;

    char* ws = (char*)d_ws;
    unsigned short* xb   = (unsigned short*)(ws);                     // 9216*256*2  = 4718592
    unsigned short* wt   = (unsigned short*)(ws + 4718592);           // 3*256*256*2 = 393216
    unsigned short* qbuf = (unsigned short*)(ws + 5111808);           // 4718592
    unsigned short* kbuf = (unsigned short*)(ws + 9830400);           // 4718592
    unsigned short* vtg  = (unsigned short*)(ws + 14548992);          // 4718592 (V transposed)

    k_prep_x<<<dim3(M_ROWS * C_ / 1024), dim3(256), 0, stream>>>(x, xb);
    k_prep_w<<<dim3(16, 3), dim3(256), 0, stream>>>(wq, wk, wv, wt);
    k_proj<<<dim3(M_ROWS / 64, 6), dim3(256), 0, stream>>>(xb, wt, bq, bk, bv, qbuf, kbuf, vtg);
    k_attn<<<dim3(N_TOK / 128 * B_ * NH), dim3(512), 0, stream>>>(qbuf, kbuf, vtg, x, gamma, out);
}

// Round 9
// 62.682 us; speedup vs baseline: 1.1095x; 1.1095x over previous
//
#include <hip/hip_runtime.h>
#include <hip/hip_bf16.h>
#include <cstdint>

#define B_    4
#define NH    8
#define N_TOK 2304
#define D_    32
#define C_    256
#define M_ROWS (B_ * N_TOK)   // 9216
#define KVB   128
#define NT2   (N_TOK / KVB)   // 18
#define M_FIX 10.0f           // fixed softmax max (exp2 domain); scores ~N(0,1.44), |s|<~9

typedef float  f32x4  __attribute__((ext_vector_type(4)));
typedef short  bf16x8 __attribute__((ext_vector_type(8)));

#define GLOADLDS(g, l) __builtin_amdgcn_global_load_lds( \
    (const __attribute__((address_space(1))) unsigned*)(g), \
    (__attribute__((address_space(3))) unsigned*)(l), 16, 0, 0)

static __device__ __forceinline__ unsigned short f2bf(float f) {
    union { float f; unsigned u; } v; v.f = f;
    unsigned u = v.u;
    u += 0x7FFF + ((u >> 16) & 1);   // round-to-nearest-even
    return (unsigned short)(u >> 16);
}

// hardware packed f32->bf16 (RTNE), lo = a, hi = b
static __device__ __forceinline__ unsigned cvt_pk_bf16(float a, float b) {
    unsigned r;
    asm("v_cvt_pk_bf16_f32 %0, %1, %2" : "=v"(r) : "v"(a), "v"(b));
    return r;
}

// ---------------- prep: X fp32 -> bf16 ----------------
__global__ void k_prep_x(const float* __restrict__ x, unsigned short* __restrict__ xb) {
    int i = blockIdx.x * blockDim.x + threadIdx.x;    // one float4 per thread
    float4 v = reinterpret_cast<const float4*>(x)[i];
    ushort4 o;
    o.x = f2bf(v.x); o.y = f2bf(v.y); o.z = f2bf(v.z); o.w = f2bf(v.w);
    reinterpret_cast<ushort4*>(xb)[i] = o;
}

// ---------------- prep: W[c][d] fp32 -> Wt[d][c] bf16 (3 matrices) ----------------
// Output wt is [768][256]: row = concat output col (Q 0-255 | K 256-511 | V 512-767).
__global__ void k_prep_w(const float* __restrict__ w0, const float* __restrict__ w1,
                         const float* __restrict__ w2, unsigned short* __restrict__ wt) {
    __shared__ float tile[64][65];
    int mat = blockIdx.y;
    const float* w = (mat == 0) ? w0 : (mat == 1) ? w1 : w2;
    int t   = blockIdx.x;           // 0..15
    int tc  = (t & 3) * 64;         // c-tile base
    int td  = (t >> 2) * 64;        // d-tile base
    int tid = threadIdx.x;
    int r0  = tid >> 6;             // 0..3
    int x0  = tid & 63;
#pragma unroll
    for (int it = 0; it < 16; ++it) {
        int c = it * 4 + r0;
        tile[c][x0] = w[(tc + c) * C_ + td + x0];
    }
    __syncthreads();
    unsigned short* wto = wt + mat * (C_ * C_);
#pragma unroll
    for (int it = 0; it < 16; ++it) {
        int d = it * 4 + r0;
        wto[(td + d) * C_ + tc + x0] = f2bf(tile[x0][d]);
    }
}

// ---------------- QKV projection: LDS-staged dbuf MFMA GEMM 9216x768x256 ----------------
// grid (144, 6). Block: 64 rows x 128 cols; 4 waves 2x2, wave = 32x64 (2x4 frags).
__global__ __launch_bounds__(256) void k_proj(
    const unsigned short* __restrict__ xb,
    const unsigned short* __restrict__ wtb,
    const float* __restrict__ bq, const float* __restrict__ bk, const float* __restrict__ bv,
    unsigned short* __restrict__ qo, unsigned short* __restrict__ ko, unsigned short* __restrict__ vto)
{
    __shared__ __align__(16) unsigned short A_lds[2][64][32];    // 8 KB
    __shared__ __align__(16) unsigned short B_lds[2][128][32];   // 16 KB

    int rows0 = blockIdx.x * 64;
    int cols0 = blockIdx.y * 128;
    int mat   = cols0 >> 8;                   // constant per block (128 | 256)
    const float* bias = (mat == 0) ? bq : (mat == 1) ? bk : bv;
    float scale = (mat == 0) ? (0.17677669529663687f * 1.4426950408889634f) : 1.0f;

    int tid = threadIdx.x, wave = tid >> 6, lane = tid & 63;
    int lr = lane & 15, lg = lane >> 4;
    int wr = wave >> 1, wc = wave & 1;

    int srow = lane >> 2, sslot = lane & 3;
    int ra   = wave * 16 + srow;
    int keyA = ((ra >> 1) & 1) | (((ra >> 3) & 1) << 1);
    const unsigned short* asrc = xb + (rows0 + ra) * C_ + ((sslot ^ keyA) * 8);
    int rb   = wave * 32 + srow;
    int keyB0 = ((rb >> 1) & 1) | (((rb >> 3) & 1) << 1);
    int keyB1 = (((rb + 16) >> 1) & 1) | ((((rb + 16) >> 3) & 1) << 1);
    const unsigned short* bsrc0 = wtb + (cols0 + rb) * C_ + ((sslot ^ keyB0) * 8);
    const unsigned short* bsrc1 = wtb + (cols0 + rb + 16) * C_ + ((sslot ^ keyB1) * 8);

    char* aldsb = (char*)&A_lds[0][0][0];
    char* bldsb = (char*)&B_lds[0][0][0];
    int adst = wave * 1024;
    int bdst0 = wave * 2048, bdst1 = bdst0 + 1024;

    int xorb = (((lr >> 1) & 1) << 4) | (((lr >> 3) & 1) << 5);
    int fcol = (lg * 16) ^ xorb;
    int arow0 = wr * 32 + lr;
    int brow0 = wc * 64 + lr;

    GLOADLDS(asrc, aldsb + adst);
    GLOADLDS(bsrc0, bldsb + bdst0);
    GLOADLDS(bsrc1, bldsb + bdst1);
    __syncthreads();

    f32x4 acc[2][4];
#pragma unroll
    for (int i = 0; i < 2; ++i)
#pragma unroll
        for (int j = 0; j < 4; ++j) acc[i][j] = (f32x4){0.f, 0.f, 0.f, 0.f};

    int buf = 0;
    for (int ks = 0; ks < 8; ++ks) {
        if (ks < 7) {
            int ko_ = (ks + 1) * 32;
            char* ad = aldsb + (buf ^ 1) * 4096;
            char* bd = bldsb + (buf ^ 1) * 8192;
            GLOADLDS(asrc + ko_, ad + adst);
            GLOADLDS(bsrc0 + ko_, bd + bdst0);
            GLOADLDS(bsrc1 + ko_, bd + bdst1);
        }
        const char* ac = aldsb + buf * 4096;
        const char* bc = bldsb + buf * 8192;

        bf16x8 a[2], b[4];
#pragma unroll
        for (int fr = 0; fr < 2; ++fr)
            a[fr] = *reinterpret_cast<const bf16x8*>(ac + (arow0 + fr * 16) * 64 + fcol);
#pragma unroll
        for (int fn = 0; fn < 4; ++fn)
            b[fn] = *reinterpret_cast<const bf16x8*>(bc + (brow0 + fn * 16) * 64 + fcol);

        __builtin_amdgcn_s_setprio(1);
#pragma unroll
        for (int fr = 0; fr < 2; ++fr)
#pragma unroll
            for (int fn = 0; fn < 4; ++fn)
                acc[fr][fn] = __builtin_amdgcn_mfma_f32_16x16x32_bf16(a[fr], b[fn], acc[fr][fn], 0, 0, 0);
        __builtin_amdgcn_s_setprio(0);

        __syncthreads();
        buf ^= 1;
    }

    int bidx = rows0 / N_TOK;
    int nb   = rows0 - bidx * N_TOK + wr * 32 + lg * 4;

    if (mat == 2) {
#pragma unroll
        for (int fr = 0; fr < 2; ++fr)
#pragma unroll
            for (int fn = 0; fn < 4; ++fn) {
                int cm = (cols0 & 255) + wc * 64 + fn * 16 + lr;
                float bsv = bias[cm];
                int hh = cm >> 5, d = cm & 31;
                uint2 pr;
                pr.x = cvt_pk_bf16(acc[fr][fn][0] + bsv, acc[fr][fn][1] + bsv);
                pr.y = cvt_pk_bf16(acc[fr][fn][2] + bsv, acc[fr][fn][3] + bsv);
                *reinterpret_cast<uint2*>(vto + ((bidx * NH + hh) * D_ + d) * N_TOK + nb + fr * 16) = pr;
            }
    } else {
        unsigned short* dst = (mat == 0) ? qo : ko;
#pragma unroll
        for (int fr = 0; fr < 2; ++fr)
#pragma unroll
            for (int fn = 0; fn < 4; ++fn) {
                int cm = (cols0 & 255) + wc * 64 + fn * 16 + lr;
                float bsv = bias[cm];
                int hh = cm >> 5, d = cm & 31;
#pragma unroll
                for (int j = 0; j < 4; ++j) {
                    float val = (acc[fr][fn][j] + bsv) * scale;
                    dst[((bidx * NH + hh) * N_TOK + nb + fr * 16 + j) * D_ + d] = f2bf(val);
                }
            }
    }
}

// ---------------- fused flash attention + residual epilogue ----------------
// 8 waves / 512 threads, 128 q-rows per block, grid 576. Waves 0-3 stage K,
// waves 4-7 stage Vt (2 x global_load_lds each). Swapped QK^T with PERMUTED
// K rows (s IS the PV A-fragment). FIXED-MAX softmax (C-init = -M_FIX),
// row-sum l via MFMA with B=ones. exp2/cvt/PV interleaved per kseg.
// NOTE: min-waves/EU = 4 (VGPR cap 128): kernel uses ~60 VGPR; capping at 8
// waves/EU (64 VGPR) forced VGPR=32 + scratch spills (R8: +30 MB HBM traffic).
__global__ __launch_bounds__(512, 4) void k_attn(
    const unsigned short* __restrict__ qb,
    const unsigned short* __restrict__ kb,
    const unsigned short* __restrict__ vtg,   // [bh][32][2304]
    const float* __restrict__ x,
    const float* __restrict__ gamma_p,
    float* __restrict__ out)
{
    __shared__ __align__(16) unsigned short K_lds[2][KVB][32];    // 16 KB
    __shared__ __align__(16) unsigned short Vt_lds[2][32][KVB];   // 16 KB

    // bijective XCD swizzle: 576 workgroups, 8 XCDs, 72 per XCD
    int wid = (blockIdx.x & 7) * 72 + (blockIdx.x >> 3);
    int bh  = wid / 18;              // b*8 + head
    int qb0 = (wid % 18) * 128;

    int tid = threadIdx.x, wave = tid >> 6, lane = tid & 63;
    int lr = lane & 15, lg = lane >> 4;

    const unsigned short* Q  = qb  + bh * N_TOK * D_;
    const unsigned short* K  = kb  + bh * N_TOK * D_;
    const unsigned short* Vt = vtg + bh * D_ * N_TOK;

    // Q as B-operand: lane holds Q[q=lr][8*lg+i]
    int qrow = qb0 + wave * 16 + lr;
    bf16x8 q_frag = *reinterpret_cast<const bf16x8*>(Q + qrow * D_ + lg * 8);

    // ---- staging: waves 0-3 stage K chunks, waves 4-7 stage Vt chunks ----
    bool stK = wave < 4;
    int  sw  = stK ? wave : (wave - 4);
    int c0   = sw * 2;
    // K rows 32sw+(lane>>2), +16 (key bits {1,3} identical for +16)
    int kr0  = 32 * sw + (lane >> 2);
    int kslot = ((kr0 >> 1) & 1) | (((kr0 >> 3) & 1) << 1);
    int koff0 = kr0 * D_ + (((lane & 3) ^ kslot) * 8);
    int koff1 = koff0 + 16 * D_;
    // Vt rows 8sw+(lane>>4), +4
    int vr0   = 8 * sw + (lane >> 4);
    int voff0 = vr0 * N_TOK + (((lane & 15) ^ (vr0 & 7)) * 8);
    int voff1 = (vr0 + 4) * N_TOK + (((lane & 15) ^ ((vr0 + 4) & 7)) * 8);

    char* kldsb = (char*)&K_lds[0][0][0];
    char* vldsb = (char*)&Vt_lds[0][0][0];
    int dst0 = c0 * 1024, dst1 = dst0 + 1024;

    // prologue: stage tile 0 into buffer 0
    if (stK) {
        GLOADLDS(K + koff0, kldsb + dst0);
        GLOADLDS(K + koff1, kldsb + dst1);
    } else {
        GLOADLDS(Vt + voff0, vldsb + dst0);
        GLOADLDS(Vt + voff1, vldsb + dst1);
    }
    __syncthreads();

    f32x4 acc0  = (f32x4){0.f, 0.f, 0.f, 0.f};   // d = lr      , q = 4lg+j
    f32x4 acc1  = (f32x4){0.f, 0.f, 0.f, 0.f};   // d = 16 + lr , q = 4lg+j
    f32x4 acc_l = (f32x4){0.f, 0.f, 0.f, 0.f};   // l(q=4lg+j), replicated over lr

    union { unsigned w[4]; bf16x8 v; } ones;
    ones.w[0] = 0x3F803F80u; ones.w[1] = 0x3F803F80u;
    ones.w[2] = 0x3F803F80u; ones.w[3] = 0x3F803F80u;

    // K read: row R(kt,lr) swizzled; per-lane part precomputed
    int kread_key = (((lr >> 1) & 1) << 4) | (((lr >> 2) & 1) << 5);
    int krow_lane = (8 * (lr >> 2) + (lr & 3)) * 64 + ((lg * 16) ^ kread_key);
    int vkey = (lr & 7) << 4;

    const f32x4 zinit = (f32x4){-M_FIX, -M_FIX, -M_FIX, -M_FIX};

    int buf = 0;
    for (int t = 0; t < NT2; ++t) {
        // async-stage next tile into other buffer (drained by end-of-iter barrier)
        if (t < NT2 - 1) {
            if (stK) {
                const unsigned short* Kn = K + (t + 1) * (KVB * D_);
                char* kd = kldsb + (buf ^ 1) * 8192;
                GLOADLDS(Kn + koff0, kd + dst0);
                GLOADLDS(Kn + koff1, kd + dst1);
            } else {
                const unsigned short* Vn = Vt + (t + 1) * KVB;
                char* vd = vldsb + (buf ^ 1) * 8192;
                GLOADLDS(Vn + voff0, vd + dst0);
                GLOADLDS(Vn + voff1, vd + dst1);
            }
        }
        const char* kc = kldsb + buf * 8192;
        const char* vc = vldsb + buf * 8192;

        // ---- S^T = K*Q - M : s[kt][j] = S[q=lr][32(kt>>1)+4(kt&1)+8lg+j] - M ----
        f32x4 s[8];
        __builtin_amdgcn_s_setprio(1);
#pragma unroll
        for (int kt = 0; kt < 8; ++kt) {
            bf16x8 kf = *reinterpret_cast<const bf16x8*>(
                kc + (kt >> 1) * 2048 + (kt & 1) * 256 + krow_lane);
            s[kt] = __builtin_amdgcn_mfma_f32_16x16x32_bf16(kf, q_frag, zinit, 0, 0, 0);
        }
        __builtin_amdgcn_s_setprio(0);

        // ---- per kseg: exp2 (TRANS) -> cvt_pk -> PV (MFMA); TRANS of kseg g+1
        //      overlaps MFMA drain of kseg g ----
#pragma unroll
        for (int kseg = 0; kseg < 4; ++kseg) {
            float e0 = __builtin_amdgcn_exp2f(s[2 * kseg][0]);
            float e1 = __builtin_amdgcn_exp2f(s[2 * kseg][1]);
            float e2 = __builtin_amdgcn_exp2f(s[2 * kseg][2]);
            float e3 = __builtin_amdgcn_exp2f(s[2 * kseg][3]);
            float e4 = __builtin_amdgcn_exp2f(s[2 * kseg + 1][0]);
            float e5 = __builtin_amdgcn_exp2f(s[2 * kseg + 1][1]);
            float e6 = __builtin_amdgcn_exp2f(s[2 * kseg + 1][2]);
            float e7 = __builtin_amdgcn_exp2f(s[2 * kseg + 1][3]);
            union { unsigned w[4]; bf16x8 v; } pa;
            pa.w[0] = cvt_pk_bf16(e0, e1);
            pa.w[1] = cvt_pk_bf16(e2, e3);
            pa.w[2] = cvt_pk_bf16(e4, e5);
            pa.w[3] = cvt_pk_bf16(e6, e7);
            int off = (kseg * 64 + lg * 16) ^ vkey;
            bf16x8 vf0 = *reinterpret_cast<const bf16x8*>(vc + lr * 256 + off);
            bf16x8 vf1 = *reinterpret_cast<const bf16x8*>(vc + (16 + lr) * 256 + off);
            acc0  = __builtin_amdgcn_mfma_f32_16x16x32_bf16(pa.v, vf0,    acc0,  0, 0, 0);
            acc1  = __builtin_amdgcn_mfma_f32_16x16x32_bf16(pa.v, vf1,    acc1,  0, 0, 0);
            acc_l = __builtin_amdgcn_mfma_f32_16x16x32_bf16(pa.v, ones.v, acc_l, 0, 0, 0);
        }

        __syncthreads();   // drains vmcnt -> staged tile visible; LDS reuse safe
        buf ^= 1;
    }

    // ---- epilogue: out = gamma * (O / l) + x  (l already in q=4lg+j domain) ----
    float g = gamma_p[0];
    int b = bh >> 3, head = bh & 7;
#pragma unroll
    for (int j = 0; j < 4; ++j) {
        float linv = 1.0f / acc_l[j];
        int n = qb0 + wave * 16 + 4 * lg + j;
        long r = (long)(b * N_TOK + n) * C_ + head * 32;
        out[r + lr]      = g * (acc0[j] * linv) + x[r + lr];
        out[r + 16 + lr] = g * (acc1[j] * linv) + x[r + 16 + lr];
    }
}

extern "C" void kernel_launch(void* const* d_in, const int* in_sizes, int n_in,
                              void* d_out, int out_size, void* d_ws, size_t ws_size,
                              hipStream_t stream) {
    const float* x     = (const float*)d_in[0];
    const float* wq    = (const float*)d_in[1];
    const float* bq    = (const float*)d_in[2];
    const float* wk    = (const float*)d_in[3];
    const float* bk    = (const float*)d_in[4];
    const float* wv    = (const float*)d_in[5];
    const float* bv    = (const float*)d_in[6];
    const float* gamma = (const float*)d_in[7];
    float* out = (float*)d_out;

    char* ws = (char*)d_ws;
    unsigned short* xb   = (unsigned short*)(ws);                     // 9216*256*2  = 4718592
    unsigned short* wt   = (unsigned short*)(ws + 4718592);           // 3*256*256*2 = 393216
    unsigned short* qbuf = (unsigned short*)(ws + 5111808);           // 4718592
    unsigned short* kbuf = (unsigned short*)(ws + 9830400);           // 4718592
    unsigned short* vtg  = (unsigned short*)(ws + 14548992);          // 4718592 (V transposed)

    k_prep_x<<<dim3(M_ROWS * C_ / 1024), dim3(256), 0, stream>>>(x, xb);
    k_prep_w<<<dim3(16, 3), dim3(256), 0, stream>>>(wq, wk, wv, wt);
    k_proj<<<dim3(M_ROWS / 64, 6), dim3(256), 0, stream>>>(xb, wt, bq, bk, bv, qbuf, kbuf, vtg);
    k_attn<<<dim3(N_TOK / 128 * B_ * NH), dim3(512), 0, stream>>>(qbuf, kbuf, vtg, x, gamma, out);
}